// Round 5
// baseline (11172.837 us; speedup 1.0000x reference)
//
#include <hip/hip_runtime.h>
#include <hip/hip_bf16.h>
#include <cstdint>

#define BATCH 64
#define SEQ   512
#define DIM   512
#define MTOT  (BATCH*SEQ)   // 32768

// RNN decomposition: 8 column-slices x 16 batch-groups (4 rows each) = 128 wgs.
// bid = slice*GRP + grp -> a group's 8 wgs sit at bids == grp (mod 8): same XCD
// under round-robin dispatch (perf heuristic only; agent-scope ops keep it
// correct regardless).
#define CSL 8     // column slices (64 cols each; W slice = 64 VGPRs/thread)
#define GRP 16    // batch groups
#define RPG 4     // rows per group
#define FSTRIDE 16  // ints per flag (64 B padding -> no shared lines)

// ---------------------------------------------------------------------------
// Kernel 0: pack W_hh [c][j] -> Wpk[jb][c] (float4 over j%4); zero flags.
// ---------------------------------------------------------------------------
__global__ __launch_bounds__(128) void pack_w(const float* __restrict__ W,
                                              float4* __restrict__ Wpk,
                                              int* __restrict__ flags) {
    const int c  = blockIdx.x;
    const int jb = threadIdx.x;
    const float4 v = *(const float4*)&W[(size_t)c * DIM + 4 * jb];
    Wpk[(size_t)jb * DIM + c] = v;
    if (blockIdx.x < GRP) flags[blockIdx.x * (CSL * FSTRIDE) + threadIdx.x] = 0;
}

// ---------------------------------------------------------------------------
// Kernel 1: fused embedding gather + input projection (NT GEMM, fp32)
// ---------------------------------------------------------------------------
__global__ __launch_bounds__(256) void embed_proj(
    const int*   __restrict__ xidx,
    const float* __restrict__ emb,
    const float* __restrict__ W_ih,
    const float* __restrict__ b_ih,
    const float* __restrict__ b_hh,
    float*       __restrict__ xp) {
    __shared__ float As[64][68];  // As[k][m]
    __shared__ float Bs[64][68];  // Bs[k][n]

    const int m0  = blockIdx.x * 64;
    const int n0  = blockIdx.y * 64;
    const int tid = threadIdx.x;

    const int lr = tid >> 4;
    const int lc = (tid & 15) << 2;

    int rows[4];
#pragma unroll
    for (int i = 0; i < 4; i++) rows[i] = xidx[m0 + lr + 16 * i];

    const int tm = (tid & 15) << 2;
    const int tn = (tid >> 4) << 2;

    float acc[4][4];
#pragma unroll
    for (int i = 0; i < 4; i++)
#pragma unroll
        for (int j = 0; j < 4; j++) acc[i][j] = 0.0f;

    for (int k0 = 0; k0 < DIM; k0 += 64) {
#pragma unroll
        for (int i = 0; i < 4; i++) {
            const int rl = lr + 16 * i;
            const float4 a = *(const float4*)&emb[(size_t)rows[i] * DIM + k0 + lc];
            As[lc + 0][rl] = a.x; As[lc + 1][rl] = a.y;
            As[lc + 2][rl] = a.z; As[lc + 3][rl] = a.w;
            const float4 b = *(const float4*)&W_ih[(size_t)(n0 + rl) * DIM + k0 + lc];
            Bs[lc + 0][rl] = b.x; Bs[lc + 1][rl] = b.y;
            Bs[lc + 2][rl] = b.z; Bs[lc + 3][rl] = b.w;
        }
        __syncthreads();
#pragma unroll 8
        for (int kk = 0; kk < 64; kk++) {
            const float4 a = *(const float4*)&As[kk][tm];
            const float4 b = *(const float4*)&Bs[kk][tn];
            acc[0][0] = fmaf(a.x, b.x, acc[0][0]);
            acc[0][1] = fmaf(a.x, b.y, acc[0][1]);
            acc[0][2] = fmaf(a.x, b.z, acc[0][2]);
            acc[0][3] = fmaf(a.x, b.w, acc[0][3]);
            acc[1][0] = fmaf(a.y, b.x, acc[1][0]);
            acc[1][1] = fmaf(a.y, b.y, acc[1][1]);
            acc[1][2] = fmaf(a.y, b.z, acc[1][2]);
            acc[1][3] = fmaf(a.y, b.w, acc[1][3]);
            acc[2][0] = fmaf(a.z, b.x, acc[2][0]);
            acc[2][1] = fmaf(a.z, b.y, acc[2][1]);
            acc[2][2] = fmaf(a.z, b.z, acc[2][2]);
            acc[2][3] = fmaf(a.z, b.w, acc[2][3]);
            acc[3][0] = fmaf(a.w, b.x, acc[3][0]);
            acc[3][1] = fmaf(a.w, b.y, acc[3][1]);
            acc[3][2] = fmaf(a.w, b.z, acc[3][2]);
            acc[3][3] = fmaf(a.w, b.w, acc[3][3]);
        }
        __syncthreads();
    }

    const int n = n0 + tn;
    const float bias0 = b_ih[n + 0] + b_hh[n + 0];
    const float bias1 = b_ih[n + 1] + b_hh[n + 1];
    const float bias2 = b_ih[n + 2] + b_hh[n + 2];
    const float bias3 = b_ih[n + 3] + b_hh[n + 3];
#pragma unroll
    for (int i = 0; i < 4; i++) {
        float4 o;
        o.x = acc[i][0] + bias0;
        o.y = acc[i][1] + bias1;
        o.z = acc[i][2] + bias2;
        o.w = acc[i][3] + bias3;
        *(float4*)&xp[(size_t)(m0 + tm + i) * DIM + n] = o;
    }
}

// ---------------------------------------------------------------------------
// Kernel 2: RNN scan, W column-split across CUs, register-resident.
//  Thread (c = tid&63, ks = tid>>6): wreg[16] float4 = W[cols col0+c][k-slice]
//  (64 VGPRs — fits default 128 budget; R2/R3's 128-reg array spilled).
//  Per step: fma over k-slice -> LDS k-reduction -> tanh -> h exchange via
//  parity-double-buffered global region + padded per-(grp,slice) seq flags.
// ---------------------------------------------------------------------------
__global__ __launch_bounds__(512)
void rnn_scan(const float4* __restrict__ Wpk, float* __restrict__ buf,
              float* __restrict__ hglob, int* __restrict__ flags) {
    __shared__ float4 h4f4[4 * 128];   // h rows [r][jb]  (8 KB)
    __shared__ float  part[8 * 256];   // k-partials      (8 KB)

    const int tid   = threadIdx.x;
    const int slice = blockIdx.x / GRP;
    const int grp   = blockIdx.x % GRP;
    const int c     = tid & 63;
    const int ks    = tid >> 6;
    const int b0    = grp * RPG;
    const int col0  = slice * 64;
    const int hb    = ks * 16;

    // register-resident W slice: jb = ks*16+i, column col0+c (coalesced load)
    float4 wreg[16];
#pragma unroll
    for (int i = 0; i < 16; i++)
        wreg[i] = Wpk[(size_t)(hb + i) * DIM + col0 + c];

    h4f4[tid] = make_float4(0.f, 0.f, 0.f, 0.f);
    __syncthreads();

    int* myflag = flags + grp * (CSL * FSTRIDE) + slice * FSTRIDE;

    for (int t = 0; t < SEQ; t++) {
        float p0 = 0.f, p1 = 0.f, p2 = 0.f, p3 = 0.f;
#pragma unroll
        for (int i = 0; i < 16; i++) {
            const float4 w  = wreg[i];
            const float4 h0 = h4f4[0 * 128 + hb + i];
            const float4 h1 = h4f4[1 * 128 + hb + i];
            const float4 h2 = h4f4[2 * 128 + hb + i];
            const float4 h3 = h4f4[3 * 128 + hb + i];
            p0 = fmaf(w.x, h0.x, p0); p0 = fmaf(w.y, h0.y, p0);
            p0 = fmaf(w.z, h0.z, p0); p0 = fmaf(w.w, h0.w, p0);
            p1 = fmaf(w.x, h1.x, p1); p1 = fmaf(w.y, h1.y, p1);
            p1 = fmaf(w.z, h1.z, p1); p1 = fmaf(w.w, h1.w, p1);
            p2 = fmaf(w.x, h2.x, p2); p2 = fmaf(w.y, h2.y, p2);
            p2 = fmaf(w.z, h2.z, p2); p2 = fmaf(w.w, h2.w, p2);
            p3 = fmaf(w.x, h3.x, p3); p3 = fmaf(w.y, h3.y, p3);
            p3 = fmaf(w.z, h3.z, p3); p3 = fmaf(w.w, h3.w, p3);
        }
        part[ks * 256 +   0 + c] = p0;
        part[ks * 256 +  64 + c] = p1;
        part[ks * 256 + 128 + c] = p2;
        part[ks * 256 + 192 + c] = p3;
        __syncthreads();

        float* hglw = hglob + ((size_t)(t & 1) * GRP + grp) * (RPG * DIM);
        if (tid < 256) {
            const int rr = tid >> 6;
            const int cc = tid & 63;
            float s = part[0 * 256 + tid];
            s += part[1 * 256 + tid];
            s += part[2 * 256 + tid];
            s += part[3 * 256 + tid];
            s += part[4 * 256 + tid];
            s += part[5 * 256 + tid];
            s += part[6 * 256 + tid];
            s += part[7 * 256 + tid];
            const size_t boff = ((size_t)(b0 + rr) * SEQ + t) * DIM + col0 + cc;
            const float pre = buf[boff] + s;
            const float hn  = tanhf(pre);
            buf[boff] = hn;   // hidden state for softmax kernel
            __hip_atomic_store(&hglw[rr * DIM + col0 + cc], hn,
                               __ATOMIC_RELAXED, __HIP_MEMORY_SCOPE_AGENT);
        }
        if (t == SEQ - 1) break;

        __threadfence();          // each storing thread: agent visibility
        __syncthreads();          // wg done (compiler drains vmcnt pre-barrier)

        if (tid == 0)
            __hip_atomic_store(myflag, t + 1, __ATOMIC_RELEASE,
                               __HIP_MEMORY_SCOPE_AGENT);
        if (tid < 64) {
            const int* fp = flags + grp * (CSL * FSTRIDE) + (tid & 7) * FSTRIDE;
            const int target = t + 1;
            while (true) {
                const int v = __hip_atomic_load(fp, __ATOMIC_ACQUIRE,
                                                __HIP_MEMORY_SCOPE_AGENT);
                if (__all(v >= target)) break;
                __builtin_amdgcn_s_sleep(1);
            }
        }
        __syncthreads();          // flags seen by wave 0 -> whole wg

        // reload h(t+1): 4 coalesced agent-scope loads per thread (bypass L1)
#pragma unroll
        for (int p = 0; p < 4; p++)
            ((float*)h4f4)[p * DIM + tid] =
                __hip_atomic_load(&hglw[p * DIM + tid], __ATOMIC_RELAXED,
                                  __HIP_MEMORY_SCOPE_AGENT);
        __syncthreads();
    }
}

// ---------------------------------------------------------------------------
// Kernel 3: softmax over H (per b,t) + transpose [B][T][H] -> out [B][H][T]
// ---------------------------------------------------------------------------
__global__ __launch_bounds__(256) void softmax_T(const float* __restrict__ hid,
                                                 float* __restrict__ out) {
    __shared__ float rowmax[64];
    __shared__ float rowinv[64];
    __shared__ float tile[64][65];

    const int b   = blockIdx.x;
    const int t0  = blockIdx.y * 64;
    const int tid = threadIdx.x;
    const float* base = hid + ((size_t)b * SEQ + t0) * DIM;

    const int r = tid >> 2;
    const int p = tid & 3;

    float m = -1e30f;
#pragma unroll 4
    for (int k = 0; k < 32; k++) {
        const float4 v = *(const float4*)&base[r * DIM + ((k * 4 + p) << 2)];
        m = fmaxf(m, fmaxf(fmaxf(v.x, v.y), fmaxf(v.z, v.w)));
    }
    m = fmaxf(m, __shfl_xor(m, 1));
    m = fmaxf(m, __shfl_xor(m, 2));

    float s = 0.0f;
#pragma unroll 4
    for (int k = 0; k < 32; k++) {
        const float4 v = *(const float4*)&base[r * DIM + ((k * 4 + p) << 2)];
        s += expf(v.x - m) + expf(v.y - m) + expf(v.z - m) + expf(v.w - m);
    }
    s += __shfl_xor(s, 1);
    s += __shfl_xor(s, 2);
    if (p == 0) {
        rowmax[r] = m;
        rowinv[r] = 1.0f / s;
    }
    __syncthreads();

    for (int hc = 0; hc < 8; hc++) {
#pragma unroll
        for (int i = 0; i < 16; i++) {
            const int lin = tid + 256 * i;
            const int rr  = lin >> 6;
            const int cc  = lin & 63;
            const float v = base[rr * DIM + hc * 64 + cc];
            tile[cc][rr] = expf(v - rowmax[rr]) * rowinv[rr];
        }
        __syncthreads();
#pragma unroll
        for (int i = 0; i < 16; i++) {
            const int lin = tid + 256 * i;
            const int hh  = lin >> 6;
            const int tt  = lin & 63;
            out[((size_t)b * DIM + hc * 64 + hh) * SEQ + t0 + tt] = tile[hh][tt];
        }
        __syncthreads();
    }
}

// ---------------------------------------------------------------------------
extern "C" void kernel_launch(void* const* d_in, const int* in_sizes, int n_in,
                              void* d_out, int out_size, void* d_ws, size_t ws_size,
                              hipStream_t stream) {
    const int*   x    = (const int*)  d_in[0];
    const float* emb  = (const float*)d_in[1];
    const float* W_ih = (const float*)d_in[2];
    const float* W_hh = (const float*)d_in[3];
    const float* b_ih = (const float*)d_in[4];
    const float* b_hh = (const float*)d_in[5];
    float* out = (float*)d_out;

    // 64 MB scratch: xp (then hid, in place) as [B][T][H]
    float* buf = (float*)d_ws;
    // staging inside d_out (16.7M floats); all consumed before softmax_T
    // overwrites d_out (stream-ordered):
    float4* Wpk   = (float4*)out;            // 1M floats
    float*  hglob = out + (4 << 20);         // 2*16*2048 floats
    int*    flags = (int*)(out + (8 << 20)); // 16*8 flags, 64B-padded

    pack_w<<<dim3(DIM), 128, 0, stream>>>(W_hh, Wpk, flags);
    embed_proj<<<dim3(MTOT / 64, DIM / 64), 256, 0, stream>>>(x, emb, W_ih, b_ih, b_hh, buf);
    rnn_scan<<<CSL * GRP, 512, 0, stream>>>(Wpk, buf, hglob, flags);
    softmax_T<<<dim3(BATCH, SEQ / 64), 256, 0, stream>>>(buf, out);
}

// Round 6
// 2271.435 us; speedup vs baseline: 4.9188x; 4.9188x over previous
//
#include <hip/hip_runtime.h>
#include <hip/hip_bf16.h>
#include <cstdint>

#define BATCH 64
#define SEQ   512
#define DIM   512
#define MTOT  (BATCH*SEQ)   // 32768

// RNN decomposition: 8 column-slices x 16 batch-groups (4 rows each) = 128 wgs.
#define CSL 8     // column slices (64 cols each)
#define GRP 16    // batch groups
#define RPG 4     // rows per group
#define FSTRIDE 16  // ints per flag (64 B padding -> no shared lines)

// ---------------------------------------------------------------------------
// Kernel 0: pack W_hh [c][j] -> Wpk[jb][c] (float4 over j%4); zero flags.
// ---------------------------------------------------------------------------
__global__ __launch_bounds__(128) void pack_w(const float* __restrict__ W,
                                              float4* __restrict__ Wpk,
                                              int* __restrict__ flags) {
    const int c  = blockIdx.x;
    const int jb = threadIdx.x;
    const float4 v = *(const float4*)&W[(size_t)c * DIM + 4 * jb];
    Wpk[(size_t)jb * DIM + c] = v;
    if (blockIdx.x < GRP) flags[blockIdx.x * (CSL * FSTRIDE) + threadIdx.x] = 0;
}

// ---------------------------------------------------------------------------
// Kernel 1: fused embedding gather + input projection (NT GEMM, fp32)
// ---------------------------------------------------------------------------
__global__ __launch_bounds__(256) void embed_proj(
    const int*   __restrict__ xidx,
    const float* __restrict__ emb,
    const float* __restrict__ W_ih,
    const float* __restrict__ b_ih,
    const float* __restrict__ b_hh,
    float*       __restrict__ xp) {
    __shared__ float As[64][68];  // As[k][m]
    __shared__ float Bs[64][68];  // Bs[k][n]

    const int m0  = blockIdx.x * 64;
    const int n0  = blockIdx.y * 64;
    const int tid = threadIdx.x;

    const int lr = tid >> 4;
    const int lc = (tid & 15) << 2;

    int rows[4];
#pragma unroll
    for (int i = 0; i < 4; i++) rows[i] = xidx[m0 + lr + 16 * i];

    const int tm = (tid & 15) << 2;
    const int tn = (tid >> 4) << 2;

    float acc[4][4];
#pragma unroll
    for (int i = 0; i < 4; i++)
#pragma unroll
        for (int j = 0; j < 4; j++) acc[i][j] = 0.0f;

    for (int k0 = 0; k0 < DIM; k0 += 64) {
#pragma unroll
        for (int i = 0; i < 4; i++) {
            const int rl = lr + 16 * i;
            const float4 a = *(const float4*)&emb[(size_t)rows[i] * DIM + k0 + lc];
            As[lc + 0][rl] = a.x; As[lc + 1][rl] = a.y;
            As[lc + 2][rl] = a.z; As[lc + 3][rl] = a.w;
            const float4 b = *(const float4*)&W_ih[(size_t)(n0 + rl) * DIM + k0 + lc];
            Bs[lc + 0][rl] = b.x; Bs[lc + 1][rl] = b.y;
            Bs[lc + 2][rl] = b.z; Bs[lc + 3][rl] = b.w;
        }
        __syncthreads();
#pragma unroll 8
        for (int kk = 0; kk < 64; kk++) {
            const float4 a = *(const float4*)&As[kk][tm];
            const float4 b = *(const float4*)&Bs[kk][tn];
            acc[0][0] = fmaf(a.x, b.x, acc[0][0]);
            acc[0][1] = fmaf(a.x, b.y, acc[0][1]);
            acc[0][2] = fmaf(a.x, b.z, acc[0][2]);
            acc[0][3] = fmaf(a.x, b.w, acc[0][3]);
            acc[1][0] = fmaf(a.y, b.x, acc[1][0]);
            acc[1][1] = fmaf(a.y, b.y, acc[1][1]);
            acc[1][2] = fmaf(a.y, b.z, acc[1][2]);
            acc[1][3] = fmaf(a.y, b.w, acc[1][3]);
            acc[2][0] = fmaf(a.z, b.x, acc[2][0]);
            acc[2][1] = fmaf(a.z, b.y, acc[2][1]);
            acc[2][2] = fmaf(a.z, b.z, acc[2][2]);
            acc[2][3] = fmaf(a.z, b.w, acc[2][3]);
            acc[3][0] = fmaf(a.w, b.x, acc[3][0]);
            acc[3][1] = fmaf(a.w, b.y, acc[3][1]);
            acc[3][2] = fmaf(a.w, b.z, acc[3][2]);
            acc[3][3] = fmaf(a.w, b.w, acc[3][3]);
        }
        __syncthreads();
    }

    const int n = n0 + tn;
    const float bias0 = b_ih[n + 0] + b_hh[n + 0];
    const float bias1 = b_ih[n + 1] + b_hh[n + 1];
    const float bias2 = b_ih[n + 2] + b_hh[n + 2];
    const float bias3 = b_ih[n + 3] + b_hh[n + 3];
#pragma unroll
    for (int i = 0; i < 4; i++) {
        float4 o;
        o.x = acc[i][0] + bias0;
        o.y = acc[i][1] + bias1;
        o.z = acc[i][2] + bias2;
        o.w = acc[i][3] + bias3;
        *(float4*)&xp[(size_t)(m0 + tm + i) * DIM + n] = o;
    }
}

// ---------------------------------------------------------------------------
// Kernel 2: RNN scan, W column-split across CUs.
//  KEY (R5 lesson): the step loop contains ZERO cache-maintenance ops.
//  All cross-wg traffic uses RELAXED agent-scope atomics (sc1 -> L3 coherence
//  point directly). Acquire/release/threadfence would emit buffer_inv /
//  buffer_wbl2 (whole-L2 ops) per call — that was R4/R5's 19 us/step.
//  Ordering: __syncthreads drains each thread's vmcnt before s_barrier, so
//  the post-barrier flag store physically follows all h stores at L3.
// ---------------------------------------------------------------------------
__global__ __launch_bounds__(512)
void rnn_scan(const float4* __restrict__ Wpk, float* __restrict__ buf,
              float* __restrict__ hglob, int* __restrict__ flags) {
    __shared__ float4 h4f4[4 * 128];   // h rows [r][jb]  (8 KB)
    __shared__ float  part[8 * 256];   // k-partials      (8 KB)

    const int tid   = threadIdx.x;
    const int slice = blockIdx.x / GRP;
    const int grp   = blockIdx.x % GRP;
    const int c     = tid & 63;
    const int ks    = tid >> 6;
    const int b0    = grp * RPG;
    const int col0  = slice * 64;
    const int hb    = ks * 16;

    // W slice for this thread's (k-slice, column); compiler may keep in regs
    // or re-load from L2 each step (~128 KB/step/CU = ~1.2 us, acceptable).
    float4 wreg[16];
#pragma unroll
    for (int i = 0; i < 16; i++)
        wreg[i] = Wpk[(size_t)(hb + i) * DIM + col0 + c];

    h4f4[tid] = make_float4(0.f, 0.f, 0.f, 0.f);
    __syncthreads();

    int* myflag = flags + grp * (CSL * FSTRIDE) + slice * FSTRIDE;

    for (int t = 0; t < SEQ; t++) {
        float p0 = 0.f, p1 = 0.f, p2 = 0.f, p3 = 0.f;
#pragma unroll
        for (int i = 0; i < 16; i++) {
            const float4 w  = wreg[i];
            const float4 h0 = h4f4[0 * 128 + hb + i];
            const float4 h1 = h4f4[1 * 128 + hb + i];
            const float4 h2 = h4f4[2 * 128 + hb + i];
            const float4 h3 = h4f4[3 * 128 + hb + i];
            p0 = fmaf(w.x, h0.x, p0); p0 = fmaf(w.y, h0.y, p0);
            p0 = fmaf(w.z, h0.z, p0); p0 = fmaf(w.w, h0.w, p0);
            p1 = fmaf(w.x, h1.x, p1); p1 = fmaf(w.y, h1.y, p1);
            p1 = fmaf(w.z, h1.z, p1); p1 = fmaf(w.w, h1.w, p1);
            p2 = fmaf(w.x, h2.x, p2); p2 = fmaf(w.y, h2.y, p2);
            p2 = fmaf(w.z, h2.z, p2); p2 = fmaf(w.w, h2.w, p2);
            p3 = fmaf(w.x, h3.x, p3); p3 = fmaf(w.y, h3.y, p3);
            p3 = fmaf(w.z, h3.z, p3); p3 = fmaf(w.w, h3.w, p3);
        }
        part[ks * 256 +   0 + c] = p0;
        part[ks * 256 +  64 + c] = p1;
        part[ks * 256 + 128 + c] = p2;
        part[ks * 256 + 192 + c] = p3;
        __syncthreads();

        float* hglw = hglob + ((size_t)(t & 1) * GRP + grp) * (RPG * DIM);
        if (tid < 256) {
            const int rr = tid >> 6;
            const int cc = tid & 63;
            float s = part[0 * 256 + tid];
            s += part[1 * 256 + tid];
            s += part[2 * 256 + tid];
            s += part[3 * 256 + tid];
            s += part[4 * 256 + tid];
            s += part[5 * 256 + tid];
            s += part[6 * 256 + tid];
            s += part[7 * 256 + tid];
            const size_t boff = ((size_t)(b0 + rr) * SEQ + t) * DIM + col0 + cc;
            const float pre = buf[boff] + s;
            const float hn  = tanhf(pre);
            buf[boff] = hn;   // hidden state for softmax kernel (ordinary store)
            __hip_atomic_store(&hglw[rr * DIM + col0 + cc], hn,
                               __ATOMIC_RELAXED, __HIP_MEMORY_SCOPE_AGENT);
        }
        if (t == SEQ - 1) break;

        // all threads drain own vmcnt at this barrier -> h stores are at L3
        __syncthreads();

        if (tid == 0)
            __hip_atomic_store(myflag, t + 1, __ATOMIC_RELAXED,
                               __HIP_MEMORY_SCOPE_AGENT);
        if (tid < 64) {
            const int* fp = flags + grp * (CSL * FSTRIDE) + (tid & 7) * FSTRIDE;
            const int target = t + 1;
            while (true) {
                const int v = __hip_atomic_load(fp, __ATOMIC_RELAXED,
                                                __HIP_MEMORY_SCOPE_AGENT);
                if (__all(v >= target)) break;
                __builtin_amdgcn_s_sleep(1);
            }
        }
        __syncthreads();   // flags observed by wave 0 -> whole wg

        // reload h(t+1): relaxed sc1 loads read L3 coherence point directly
#pragma unroll
        for (int p = 0; p < 4; p++)
            ((float*)h4f4)[p * DIM + tid] =
                __hip_atomic_load(&hglw[p * DIM + tid], __ATOMIC_RELAXED,
                                  __HIP_MEMORY_SCOPE_AGENT);
        __syncthreads();
    }
}

// ---------------------------------------------------------------------------
// Kernel 3: softmax over H (per b,t) + transpose [B][T][H] -> out [B][H][T]
// ---------------------------------------------------------------------------
__global__ __launch_bounds__(256) void softmax_T(const float* __restrict__ hid,
                                                 float* __restrict__ out) {
    __shared__ float rowmax[64];
    __shared__ float rowinv[64];
    __shared__ float tile[64][65];

    const int b   = blockIdx.x;
    const int t0  = blockIdx.y * 64;
    const int tid = threadIdx.x;
    const float* base = hid + ((size_t)b * SEQ + t0) * DIM;

    const int r = tid >> 2;
    const int p = tid & 3;

    float m = -1e30f;
#pragma unroll 4
    for (int k = 0; k < 32; k++) {
        const float4 v = *(const float4*)&base[r * DIM + ((k * 4 + p) << 2)];
        m = fmaxf(m, fmaxf(fmaxf(v.x, v.y), fmaxf(v.z, v.w)));
    }
    m = fmaxf(m, __shfl_xor(m, 1));
    m = fmaxf(m, __shfl_xor(m, 2));

    float s = 0.0f;
#pragma unroll 4
    for (int k = 0; k < 32; k++) {
        const float4 v = *(const float4*)&base[r * DIM + ((k * 4 + p) << 2)];
        s += expf(v.x - m) + expf(v.y - m) + expf(v.z - m) + expf(v.w - m);
    }
    s += __shfl_xor(s, 1);
    s += __shfl_xor(s, 2);
    if (p == 0) {
        rowmax[r] = m;
        rowinv[r] = 1.0f / s;
    }
    __syncthreads();

    for (int hc = 0; hc < 8; hc++) {
#pragma unroll
        for (int i = 0; i < 16; i++) {
            const int lin = tid + 256 * i;
            const int rr  = lin >> 6;
            const int cc  = lin & 63;
            const float v = base[rr * DIM + hc * 64 + cc];
            tile[cc][rr] = expf(v - rowmax[rr]) * rowinv[rr];
        }
        __syncthreads();
#pragma unroll
        for (int i = 0; i < 16; i++) {
            const int lin = tid + 256 * i;
            const int hh  = lin >> 6;
            const int tt  = lin & 63;
            out[((size_t)b * DIM + hc * 64 + hh) * SEQ + t0 + tt] = tile[hh][tt];
        }
        __syncthreads();
    }
}

// ---------------------------------------------------------------------------
extern "C" void kernel_launch(void* const* d_in, const int* in_sizes, int n_in,
                              void* d_out, int out_size, void* d_ws, size_t ws_size,
                              hipStream_t stream) {
    const int*   x    = (const int*)  d_in[0];
    const float* emb  = (const float*)d_in[1];
    const float* W_ih = (const float*)d_in[2];
    const float* W_hh = (const float*)d_in[3];
    const float* b_ih = (const float*)d_in[4];
    const float* b_hh = (const float*)d_in[5];
    float* out = (float*)d_out;

    // 64 MB scratch: xp (then hid, in place) as [B][T][H]
    float* buf = (float*)d_ws;
    // staging inside d_out (16.7M floats); all consumed before softmax_T
    // overwrites d_out (stream-ordered):
    float4* Wpk   = (float4*)out;            // 1M floats
    float*  hglob = out + (4 << 20);         // 2*16*2048 floats
    int*    flags = (int*)(out + (8 << 20)); // 16*8 flags, 64B-padded

    pack_w<<<dim3(DIM), 128, 0, stream>>>(W_hh, Wpk, flags);
    embed_proj<<<dim3(MTOT / 64, DIM / 64), 256, 0, stream>>>(x, emb, W_ih, b_ih, b_hh, buf);
    rnn_scan<<<CSL * GRP, 512, 0, stream>>>(Wpk, buf, hglob, flags);
    softmax_T<<<dim3(BATCH, SEQ / 64), 256, 0, stream>>>(buf, out);
}